// Round 1
// baseline (1954.708 us; speedup 1.0000x reference)
//
#include <hip/hip_runtime.h>
#include <math.h>

// Problem constants (fixed by setup_inputs)
#define BATCH 4
#define NTOK  16384       // 128*128
#define CDIM  512
#define NH    8
#define HD    64
#define M_ROWS (BATCH*NTOK)   // 65536
#define KDIM  512

// ---------------- kernel 0: RoPE cos/sin tables (128 x 16 per axis) --------
// tab layout (floats): cx[ t*16+i ] @0, sx @2048, cy @4096, sy @6144 (8192 total)
__global__ void rope_tables(float* __restrict__ tab) {
    int tid = threadIdx.x;
    for (int i = 0; i < 32; i++) {
        int idx = tid + i * 256;            // 0..8191
        int grp = idx >> 11;                // 0 cx, 1 sx, 2 cy, 3 sy
        int rem = idx & 2047;
        int t   = rem >> 4;
        int fi  = rem & 15;
        float freq_f = (float)pow(10.0, -(double)fi / 16.0);  // theta=10, hd=64: 10^(-i/16)
        double ang = (double)t * (double)freq_f;
        double val = (grp & 1) ? sin(ang) : cos(ang);
        tab[idx] = (float)val;
    }
}

// ---------------- fp32 tiled GEMM, 128x128 tile, BK=32, 8x8 per thread -----
// MODE 0: C = A*B + bias -> Cout            (proj GEMM, N=512)
// MODE 1: qkv GEMM (N=1536): bias + RoPE + elu+1, scatter to q/k/v arrays
template<int MODE>
__global__ __launch_bounds__(256, 3)
void gemm_k(const float* __restrict__ A, const float* __restrict__ Bm,
            const float* __restrict__ bias, int N,
            float* __restrict__ Cout,
            float* __restrict__ qd, float* __restrict__ kd, float* __restrict__ vd,
            const float* __restrict__ tab)
{
    const int BK = 32;
    __shared__ float As[BK][128 + 4];   // transposed: As[k][m]; stride 132 keeps 16B align
    __shared__ float Bs[BK][128];

    int tid = threadIdx.x;
    int tx = tid & 15;          // 16 cols of threads -> 8 output cols each
    int ty = tid >> 4;          // 16 rows of threads -> 8 output rows each
    int row0 = blockIdx.y * 128;
    int col0 = blockIdx.x * 128;

    float acc[8][8];
    #pragma unroll
    for (int r = 0; r < 8; r++)
        #pragma unroll
        for (int j = 0; j < 8; j++) acc[r][j] = 0.0f;

    for (int k0 = 0; k0 < KDIM; k0 += BK) {
        // stage A: 128 rows x 32 k  (1024 float4, 4 per thread), store transposed
        #pragma unroll
        for (int i = 0; i < 4; i++) {
            int idx = tid + i * 256;
            int r  = idx >> 3;       // row 0..127
            int kq = idx & 7;        // float4 index within the 32-wide k slice
            float4 av = *(const float4*)&A[(size_t)(row0 + r) * KDIM + k0 + kq * 4];
            As[kq*4+0][r] = av.x; As[kq*4+1][r] = av.y;
            As[kq*4+2][r] = av.z; As[kq*4+3][r] = av.w;
        }
        // stage B: 32 k x 128 cols
        #pragma unroll
        for (int i = 0; i < 4; i++) {
            int idx = tid + i * 256;
            int kr = idx >> 5;       // 0..31
            int cq = idx & 31;       // float4 col
            *(float4*)&Bs[kr][cq*4] =
                *(const float4*)&Bm[(size_t)(k0 + kr) * N + col0 + cq * 4];
        }
        __syncthreads();

        #pragma unroll 8
        for (int kk = 0; kk < BK; kk++) {
            float a[8], b[8];
            float4 t0 = *(const float4*)&As[kk][ty*8];
            float4 t1 = *(const float4*)&As[kk][ty*8+4];
            float4 t2 = *(const float4*)&Bs[kk][tx*8];
            float4 t3 = *(const float4*)&Bs[kk][tx*8+4];
            a[0]=t0.x; a[1]=t0.y; a[2]=t0.z; a[3]=t0.w;
            a[4]=t1.x; a[5]=t1.y; a[6]=t1.z; a[7]=t1.w;
            b[0]=t2.x; b[1]=t2.y; b[2]=t2.z; b[3]=t2.w;
            b[4]=t3.x; b[5]=t3.y; b[6]=t3.z; b[7]=t3.w;
            #pragma unroll
            for (int r = 0; r < 8; r++)
                #pragma unroll
                for (int j = 0; j < 8; j++)
                    acc[r][j] += a[r] * b[j];
        }
        __syncthreads();
    }

    float bv[8];
    #pragma unroll
    for (int j = 0; j < 8; j++) bv[j] = bias[col0 + tx*8 + j];

    if (MODE == 0) {
        #pragma unroll
        for (int r = 0; r < 8; r++) {
            int row = row0 + ty*8 + r;
            float4 o0, o1;
            o0.x = acc[r][0]+bv[0]; o0.y = acc[r][1]+bv[1];
            o0.z = acc[r][2]+bv[2]; o0.w = acc[r][3]+bv[3];
            o1.x = acc[r][4]+bv[4]; o1.y = acc[r][5]+bv[5];
            o1.z = acc[r][6]+bv[6]; o1.w = acc[r][7]+bv[7];
            *(float4*)&Cout[(size_t)row * N + col0 + tx*8]     = o0;
            *(float4*)&Cout[(size_t)row * N + col0 + tx*8 + 4] = o1;
        }
    } else {
        // qkv layout: col = which*512 + h*64 + d
        int which = col0 >> 9;                  // block-uniform (128 | 512)
        int hcol  = (col0 & 511) + tx*8;        // channel within the 512-wide q/k/v
        float* dst = (which == 0) ? qd : (which == 1) ? kd : vd;
        if (which == 2) {
            #pragma unroll
            for (int r = 0; r < 8; r++) {
                int row = row0 + ty*8 + r;
                float4 o0, o1;
                o0.x = acc[r][0]+bv[0]; o0.y = acc[r][1]+bv[1];
                o0.z = acc[r][2]+bv[2]; o0.w = acc[r][3]+bv[3];
                o1.x = acc[r][4]+bv[4]; o1.y = acc[r][5]+bv[5];
                o1.z = acc[r][6]+bv[6]; o1.w = acc[r][7]+bv[7];
                *(float4*)&dst[(size_t)row * CDIM + hcol]     = o0;
                *(float4*)&dst[(size_t)row * CDIM + hcol + 4] = o1;
            }
        } else {
            int ch0 = hcol & 63;                // 8-aligned; never straddles 32 or 64
            int coff[4], soff[4], fid[4], usey[4];
            #pragma unroll
            for (int p = 0; p < 4; p++) {
                int ch = ch0 + 2*p;
                if (ch < 32) { fid[p] = ch >> 1;      coff[p] = 0;    soff[p] = 2048; usey[p] = 0; }
                else         { fid[p] = (ch-32) >> 1; coff[p] = 4096; soff[p] = 6144; usey[p] = 1; }
            }
            #pragma unroll
            for (int r = 0; r < 8; r++) {
                int row = row0 + ty*8 + r;
                int t   = row & (NTOK-1);
                int txx = t & 127;
                int tyy = t >> 7;
                float o[8];
                #pragma unroll
                for (int p = 0; p < 4; p++) {
                    int tc = usey[p] ? tyy : txx;
                    float c = tab[coff[p] + tc*16 + fid[p]];
                    float s = tab[soff[p] + tc*16 + fid[p]];
                    float xr = acc[r][2*p]   + bv[2*p];
                    float xi = acc[r][2*p+1] + bv[2*p+1];
                    o[2*p]   = xr*c - xi*s;
                    o[2*p+1] = xr*s + xi*c;
                }
                #pragma unroll
                for (int j = 0; j < 8; j++)
                    o[j] = (o[j] > 0.0f) ? o[j] + 1.0f : expf(o[j]);   // elu+1
                float4 o0, o1;
                o0.x=o[0]; o0.y=o[1]; o0.z=o[2]; o0.w=o[3];
                o1.x=o[4]; o1.y=o[5]; o1.z=o[6]; o1.w=o[7];
                *(float4*)&dst[(size_t)row * CDIM + hcol]     = o0;
                *(float4*)&dst[(size_t)row * CDIM + hcol + 4] = o1;
            }
        }
    }
}

// ---------------- kernel 2: kv = k^T v (64x64 per bh) + ksum ----------------
__global__ __launch_bounds__(256, 4)
void kv_kernel(const float* __restrict__ kk, const float* __restrict__ vv,
               float* __restrict__ kv, float* __restrict__ ksum)
{
    int bh = blockIdx.x;                 // 0..31
    int b = bh >> 3, h = bh & 7;
    int t0 = blockIdx.y * 1024;          // 16 chunks of 1024 tokens
    __shared__ float ks[64][64];
    __shared__ float vs[64][64];
    int tid = threadIdx.x;
    int tx = tid & 15;                   // e4 = tx*4
    int ty = tid >> 4;                   // d4 = ty*4
    float acc[4][4];
    float ksacc[4];
    #pragma unroll
    for (int r = 0; r < 4; r++) { ksacc[r] = 0.0f;
        #pragma unroll
        for (int j = 0; j < 4; j++) acc[r][j] = 0.0f; }

    const size_t rowbase = (size_t)b * NTOK;
    for (int tt = t0; tt < t0 + 1024; tt += 64) {
        #pragma unroll
        for (int i = 0; i < 4; i++) {
            int idx = tid + i * 256;     // 0..1023: token=idx>>4, q4=idx&15
            int tok = idx >> 4, q4 = idx & 15;
            size_t g = (rowbase + tt + tok) * CDIM + h * HD + q4 * 4;
            *(float4*)&ks[tok][q4*4] = *(const float4*)&kk[g];
            *(float4*)&vs[tok][q4*4] = *(const float4*)&vv[g];
        }
        __syncthreads();
        #pragma unroll 8
        for (int t = 0; t < 64; t++) {
            float4 kd4 = *(const float4*)&ks[t][ty*4];
            float4 vd4 = *(const float4*)&vs[t][tx*4];
            float ka[4] = {kd4.x, kd4.y, kd4.z, kd4.w};
            float va[4] = {vd4.x, vd4.y, vd4.z, vd4.w};
            #pragma unroll
            for (int r = 0; r < 4; r++) {
                ksacc[r] += ka[r];
                #pragma unroll
                for (int j = 0; j < 4; j++) acc[r][j] += ka[r] * va[j];
            }
        }
        __syncthreads();
    }
    #pragma unroll
    for (int r = 0; r < 4; r++)
        #pragma unroll
        for (int j = 0; j < 4; j++)
            atomicAdd(&kv[bh*4096 + (ty*4+r)*64 + tx*4 + j], acc[r][j]);
    if (tx == 0) {
        #pragma unroll
        for (int r = 0; r < 4; r++) atomicAdd(&ksum[bh*64 + ty*4 + r], ksacc[r]);
    }
}

// ---------------- kernel 3: out = (q . kv) * z ------------------------------
__global__ __launch_bounds__(256, 4)
void attn_kernel(const float* __restrict__ q, const float* __restrict__ kv,
                 const float* __restrict__ ksum, float* __restrict__ attn)
{
    int bh = blockIdx.x;
    int b = bh >> 3, h = bh & 7;
    int rc = blockIdx.y;                 // 64 chunks of 256 rows
    __shared__ float kvs[64][64];        // kv[d][e]
    __shared__ float qs[64][68];         // padded: 68*4=272B, 16B aligned rows
    __shared__ float ksums[64];
    __shared__ float zpart[64][4];
    __shared__ float zs[64];
    int tid = threadIdx.x;
    int tx = tid & 15;                   // e4 = tx*4
    int ty = tid >> 4;                   // rows ty*4..+3

    #pragma unroll
    for (int i = 0; i < 4; i++) {
        int idx = tid + i * 256;         // 0..1023
        *(float4*)&kvs[idx >> 4][(idx & 15) * 4] = *(const float4*)&kv[bh*4096 + idx*4];
    }
    if (tid < 64) ksums[tid] = ksum[bh*64 + tid];

    for (int sub = 0; sub < 4; sub++) {
        int r0 = rc * 256 + sub * 64;
        #pragma unroll
        for (int i = 0; i < 4; i++) {
            int idx = tid + i * 256;
            int rr = idx >> 4, q4 = idx & 15;
            *(float4*)&qs[rr][q4*4] =
                *(const float4*)&q[((size_t)b * NTOK + r0 + rr) * CDIM + h * HD + q4 * 4];
        }
        __syncthreads();
        {   // z denominators
            int row = tid & 63, g = tid >> 6;
            float p = 0.0f;
            #pragma unroll
            for (int d = 0; d < 16; d++) p += qs[row][g*16 + d] * ksums[g*16 + d];
            zpart[row][g] = p;
        }
        __syncthreads();
        if (tid < 64)
            zs[tid] = 1.0f / (zpart[tid][0] + zpart[tid][1] + zpart[tid][2] + zpart[tid][3] + 1e-6f);
        __syncthreads();

        float acc[4][4];
        #pragma unroll
        for (int r = 0; r < 4; r++)
            #pragma unroll
            for (int e = 0; e < 4; e++) acc[r][e] = 0.0f;

        for (int d = 0; d < 64; d += 4) {
            float qa[4][4], ka[4][4];
            #pragma unroll
            for (int r = 0; r < 4; r++) {
                float4 v4 = *(const float4*)&qs[ty*4+r][d];
                qa[r][0]=v4.x; qa[r][1]=v4.y; qa[r][2]=v4.z; qa[r][3]=v4.w;
            }
            #pragma unroll
            for (int j = 0; j < 4; j++) {
                float4 v4 = *(const float4*)&kvs[d+j][tx*4];
                ka[j][0]=v4.x; ka[j][1]=v4.y; ka[j][2]=v4.z; ka[j][3]=v4.w;
            }
            #pragma unroll
            for (int r = 0; r < 4; r++)
                #pragma unroll
                for (int j = 0; j < 4; j++)
                    #pragma unroll
                    for (int e = 0; e < 4; e++)
                        acc[r][e] += qa[r][j] * ka[j][e];
        }
        #pragma unroll
        for (int r = 0; r < 4; r++) {
            float z = zs[ty*4 + r];
            float4 o;
            o.x = acc[r][0]*z; o.y = acc[r][1]*z; o.z = acc[r][2]*z; o.w = acc[r][3]*z;
            *(float4*)&attn[((size_t)b * NTOK + r0 + ty*4 + r) * CDIM + h * HD + tx*4] = o;
        }
        __syncthreads();
    }
}

// ---------------------------------------------------------------------------
extern "C" void kernel_launch(void* const* d_in, const int* in_sizes, int n_in,
                              void* d_out, int out_size, void* d_ws, size_t ws_size,
                              hipStream_t stream)
{
    const float* x      = (const float*)d_in[0];
    const float* w_qkv  = (const float*)d_in[1];
    const float* b_qkv  = (const float*)d_in[2];
    const float* w_proj = (const float*)d_in[3];
    const float* b_proj = (const float*)d_in[4];
    float* out = (float*)d_out;
    float* ws  = (float*)d_ws;

    const size_t NC = (size_t)M_ROWS * CDIM;     // 33,554,432 floats
    float* qw   = ws;
    float* kw   = ws + NC;
    float* vw   = ws + 2 * NC;
    float* attn = vw;                             // v no longer needed after kv_kernel
    // scratch at the head of d_out; consumed before the final GEMM overwrites it
    float* kv   = out;                            // 32*4096 floats
    float* ksum = out + 131072;                   // 32*64
    float* tabp = out + 133120;                   // 8192

    hipMemsetAsync(out, 0, (size_t)133120 * sizeof(float), stream);  // zero kv + ksum
    rope_tables<<<1, 256, 0, stream>>>(tabp);
    gemm_k<1><<<dim3(12, 512), 256, 0, stream>>>(x, w_qkv, b_qkv, 1536,
                                                 nullptr, qw, kw, vw, tabp);
    kv_kernel<<<dim3(32, 16), 256, 0, stream>>>(kw, vw, kv, ksum);
    attn_kernel<<<dim3(32, 64), 256, 0, stream>>>(qw, kv, ksum, attn);
    gemm_k<0><<<dim3(4, 512), 256, 0, stream>>>(attn, w_proj, b_proj, 512,
                                                out, nullptr, nullptr, nullptr, nullptr);
}

// Round 2
// 671.205 us; speedup vs baseline: 2.9122x; 2.9122x over previous
//
#include <hip/hip_runtime.h>
#include <math.h>

#define BATCH 4
#define NTOK  16384
#define CDIM  512
#define NH    8
#define HD    64
#define M_ROWS (BATCH*NTOK)
#define KDIM  512

typedef _Float16 f16;
typedef _Float16 f16x8 __attribute__((ext_vector_type(8)));
typedef _Float16 f16x4 __attribute__((ext_vector_type(4)));
typedef _Float16 f16x2 __attribute__((ext_vector_type(2)));
typedef float    f32x4 __attribute__((ext_vector_type(4)));

__device__ __forceinline__ void load_lds16(const void* g, void* l) {
    __builtin_amdgcn_global_load_lds(
        (const __attribute__((address_space(1))) void*)g,
        (__attribute__((address_space(3))) void*)l, 16, 0, 0);
}

__global__ void rope_tables(float* __restrict__ tab) {
    int tid = threadIdx.x;
    for (int i = 0; i < 32; i++) {
        int idx = tid + i * 256;
        int grp = idx >> 11;
        int rem = idx & 2047;
        int t   = rem >> 4;
        int fi  = rem & 15;
        float freq_f = (float)pow(10.0, -(double)fi / 16.0);
        double ang = (double)t * (double)freq_f;
        tab[idx] = (float)((grp & 1) ? sin(ang) : cos(ang));
    }
}

__global__ void convert_x_f16(const float* __restrict__ in, f16* __restrict__ outp) {
    int i = blockIdx.x * 256 + threadIdx.x;
    float4 a = *(const float4*)&in[(size_t)i * 8];
    float4 b = *(const float4*)&in[(size_t)i * 8 + 4];
    f16x8 o;
    o[0]=(f16)a.x; o[1]=(f16)a.y; o[2]=(f16)a.z; o[3]=(f16)a.w;
    o[4]=(f16)b.x; o[5]=(f16)b.y; o[6]=(f16)b.z; o[7]=(f16)b.w;
    *(f16x8*)&outp[(size_t)i * 8] = o;
}

__global__ void convert_wT(const float* __restrict__ w, f16* __restrict__ wt, int N) {
    int idx = blockIdx.x * 256 + threadIdx.x;
    int n = idx >> 9, k = idx & 511;
    wt[idx] = (f16)w[(size_t)k * N + n];
}

template<int MODE>
__global__ __launch_bounds__(256, 2)
void gemm_f16(const f16* __restrict__ A, const f16* __restrict__ Bt,
              const float* __restrict__ bias,
              float* __restrict__ Co,
              f16* __restrict__ qd, f16* __restrict__ kd, f16* __restrict__ vd,
              const float* __restrict__ tab)
{
    __shared__ f16 As[128 * 32];
    __shared__ f16 Bs[128 * 32];
    const int tid  = threadIdx.x;
    const int lane = tid & 63;
    const int wave = tid >> 6;
    const int wy = wave >> 1, wx = wave & 1;
    const int row0 = blockIdx.y * 128;
    const int col0 = blockIdx.x * 128;
    const int l15 = lane & 15;
    const int l4  = lane >> 4;

    f32x4 acc[4][4];
    #pragma unroll
    for (int mt = 0; mt < 4; mt++)
        #pragma unroll
        for (int nt = 0; nt < 4; nt++)
            acc[mt][nt] = (f32x4){0.f, 0.f, 0.f, 0.f};

    const int pbase = wave * 128;

    for (int k0 = 0; k0 < KDIM; k0 += 32) {
        #pragma unroll
        for (int i = 0; i < 2; i++) {
            int p = pbase + i * 64 + lane;
            int m = p >> 2;
            int j = p & 3;
            load_lds16(&A [(size_t)(row0 + m) * KDIM + k0 + j * 8], &As[(pbase + i * 64) * 8]);
            load_lds16(&Bt[(size_t)(col0 + m) * KDIM + k0 + j * 8], &Bs[(pbase + i * 64) * 8]);
        }
        __syncthreads();

        f16x8 af[4], bf[4];
        #pragma unroll
        for (int t = 0; t < 4; t++) {
            af[t] = *(const f16x8*)&As[(wy * 64 + t * 16 + l15) * 32 + l4 * 8];
            bf[t] = *(const f16x8*)&Bs[(wx * 64 + t * 16 + l15) * 32 + l4 * 8];
        }
        #pragma unroll
        for (int mt = 0; mt < 4; mt++)
            #pragma unroll
            for (int nt = 0; nt < 4; nt++)
                acc[mt][nt] = __builtin_amdgcn_mfma_f32_16x16x32_f16(af[mt], bf[nt], acc[mt][nt], 0, 0, 0);
        __syncthreads();
    }

    if (MODE == 0) {
        #pragma unroll
        for (int nt = 0; nt < 4; nt++) {
            int col = col0 + wx * 64 + nt * 16 + l15;
            float bv = bias[col];
            #pragma unroll
            for (int mt = 0; mt < 4; mt++)
                #pragma unroll
                for (int r = 0; r < 4; r++) {
                    int row = row0 + wy * 64 + mt * 16 + l4 * 4 + r;
                    Co[(size_t)row * CDIM + col] = acc[mt][nt][r] + bv;
                }
        }
    } else {
        const int which = col0 >> 9;
        f16* dst = (which == 0) ? qd : (which == 1) ? kd : vd;
        #pragma unroll
        for (int nt = 0; nt < 4; nt++) {
            int coln = col0 + wx * 64 + nt * 16 + l15;
            int c512 = coln & 511;
            float bv = bias[coln];
            if (which == 2) {
                #pragma unroll
                for (int mt = 0; mt < 4; mt++)
                    #pragma unroll
                    for (int r = 0; r < 4; r++) {
                        int row = row0 + wy * 64 + mt * 16 + l4 * 4 + r;
                        float val = acc[mt][nt][r] + bv;
                        float pv  = __shfl_xor(val, 1, 64);
                        if (!(lane & 1)) {
                            f16x2 pk; pk[0] = (f16)val; pk[1] = (f16)pv;
                            *(f16x2*)&dst[(size_t)row * CDIM + c512] = pk;
                        }
                    }
            } else {
                int ch  = c512 & 63;
                int isy = ch >> 5;
                int fid = (ch & 31) >> 1;
                const float* ct = tab + (isy ? 4096 : 0)    + fid;
                const float* st = tab + (isy ? 6144 : 2048) + fid;
                #pragma unroll
                for (int mt = 0; mt < 4; mt++)
                    #pragma unroll
                    for (int r = 0; r < 4; r++) {
                        int row = row0 + wy * 64 + mt * 16 + l4 * 4 + r;
                        int tok = row & (NTOK - 1);
                        int t   = isy ? (tok >> 7) : (tok & 127);
                        float c = ct[t * 16], s = st[t * 16];
                        float val = acc[mt][nt][r] + bv;
                        float pv  = __shfl_xor(val, 1, 64);
                        float xr = (lane & 1) ? pv  : val;
                        float xi = (lane & 1) ? val : pv;
                        float o_r = xr * c - xi * s;
                        float o_i = xr * s + xi * c;
                        o_r = (o_r > 0.f) ? o_r + 1.f : __expf(o_r);
                        o_i = (o_i > 0.f) ? o_i + 1.f : __expf(o_i);
                        if (!(lane & 1)) {
                            f16x2 pk; pk[0] = (f16)o_r; pk[1] = (f16)o_i;
                            *(f16x2*)&dst[(size_t)row * CDIM + c512] = pk;
                        }
                    }
            }
        }
    }
}

__global__ __launch_bounds__(256, 4)
void kv_kernel(const f16* __restrict__ kk, const f16* __restrict__ vv,
               float* __restrict__ kv, float* __restrict__ ksum)
{
    int bh = blockIdx.x;
    int b = bh >> 3, h = bh & 7;
    int t0 = blockIdx.y * 1024;
    __shared__ float ks[64][64];
    __shared__ float vs[64][64];
    int tid = threadIdx.x;
    int tx = tid & 15;
    int ty = tid >> 4;
    float acc[4][4];
    float ksacc[4];
    #pragma unroll
    for (int r = 0; r < 4; r++) { ksacc[r] = 0.f;
        #pragma unroll
        for (int j = 0; j < 4; j++) acc[r][j] = 0.f; }

    const size_t rowbase = (size_t)b * NTOK;
    for (int tt = t0; tt < t0 + 1024; tt += 64) {
        #pragma unroll
        for (int i = 0; i < 2; i++) {
            int idx = tid + i * 256;
            int tok = idx >> 3;
            int o   = (idx & 7) * 8;
            size_t g = (rowbase + tt + tok) * CDIM + h * HD + o;
            f16x8 k8 = *(const f16x8*)&kk[g];
            f16x8 v8 = *(const f16x8*)&vv[g];
            #pragma unroll
            for (int e = 0; e < 8; e++) { ks[tok][o + e] = (float)k8[e]; vs[tok][o + e] = (float)v8[e]; }
        }
        __syncthreads();
        #pragma unroll 8
        for (int t = 0; t < 64; t++) {
            float4 kd4 = *(const float4*)&ks[t][ty * 4];
            float4 vd4 = *(const float4*)&vs[t][tx * 4];
            float ka[4] = {kd4.x, kd4.y, kd4.z, kd4.w};
            float va[4] = {vd4.x, vd4.y, vd4.z, vd4.w};
            #pragma unroll
            for (int r = 0; r < 4; r++) {
                ksacc[r] += ka[r];
                #pragma unroll
                for (int j = 0; j < 4; j++) acc[r][j] += ka[r] * va[j];
            }
        }
        __syncthreads();
    }
    #pragma unroll
    for (int r = 0; r < 4; r++)
        #pragma unroll
        for (int j = 0; j < 4; j++)
            atomicAdd(&kv[bh * 4096 + (ty * 4 + r) * 64 + tx * 4 + j], acc[r][j]);
    if (tx == 0) {
        #pragma unroll
        for (int r = 0; r < 4; r++) atomicAdd(&ksum[bh * 64 + ty * 4 + r], ksacc[r]);
    }
}

__global__ __launch_bounds__(256, 4)
void attn_kernel(const f16* __restrict__ q, const float* __restrict__ kv,
                 const float* __restrict__ ksum, f16* __restrict__ attnh)
{
    int bh = blockIdx.x;
    int b = bh >> 3, h = bh & 7;
    int rc = blockIdx.y;
    __shared__ float kvs[64][64];
    __shared__ float qs[64][68];
    __shared__ float ksums[64];
    __shared__ float zpart[64][4];
    __shared__ float zs[64];
    int tid = threadIdx.x;
    int tx = tid & 15;
    int ty = tid >> 4;

    #pragma unroll
    for (int i = 0; i < 4; i++) {
        int idx = tid + i * 256;
        *(float4*)&kvs[idx >> 4][(idx & 15) * 4] = *(const float4*)&kv[bh * 4096 + idx * 4];
    }
    if (tid < 64) ksums[tid] = ksum[bh * 64 + tid];

    for (int sub = 0; sub < 4; sub++) {
        int r0 = rc * 256 + sub * 64;
        #pragma unroll
        for (int i = 0; i < 2; i++) {
            int idx = tid + i * 256;
            int rr = idx >> 3;
            int o  = (idx & 7) * 8;
            f16x8 q8 = *(const f16x8*)&q[((size_t)b * NTOK + r0 + rr) * CDIM + h * HD + o];
            #pragma unroll
            for (int e = 0; e < 8; e++) qs[rr][o + e] = (float)q8[e];
        }
        __syncthreads();
        {
            int row = tid & 63, g = tid >> 6;
            float p = 0.f;
            #pragma unroll
            for (int d = 0; d < 16; d++) p += qs[row][g * 16 + d] * ksums[g * 16 + d];
            zpart[row][g] = p;
        }
        __syncthreads();
        if (tid < 64)
            zs[tid] = 1.f / (zpart[tid][0] + zpart[tid][1] + zpart[tid][2] + zpart[tid][3] + 1e-6f);
        __syncthreads();

        float acc[4][4];
        #pragma unroll
        for (int r = 0; r < 4; r++)
            #pragma unroll
            for (int e = 0; e < 4; e++) acc[r][e] = 0.f;

        for (int d = 0; d < 64; d += 4) {
            float qa[4][4], ka[4][4];
            #pragma unroll
            for (int r = 0; r < 4; r++) {
                float4 v4 = *(const float4*)&qs[ty * 4 + r][d];
                qa[r][0]=v4.x; qa[r][1]=v4.y; qa[r][2]=v4.z; qa[r][3]=v4.w;
            }
            #pragma unroll
            for (int j = 0; j < 4; j++) {
                float4 v4 = *(const float4*)&kvs[d + j][tx * 4];
                ka[j][0]=v4.x; ka[j][1]=v4.y; ka[j][2]=v4.z; ka[j][3]=v4.w;
            }
            #pragma unroll
            for (int r = 0; r < 4; r++)
                #pragma unroll
                for (int j = 0; j < 4; j++)
                    #pragma unroll
                    for (int e = 0; e < 4; e++)
                        acc[r][e] += qa[r][j] * ka[j][e];
        }
        #pragma unroll
        for (int r = 0; r < 4; r++) {
            float z = zs[ty * 4 + r];
            f16x4 o4;
            o4[0] = (f16)(acc[r][0] * z); o4[1] = (f16)(acc[r][1] * z);
            o4[2] = (f16)(acc[r][2] * z); o4[3] = (f16)(acc[r][3] * z);
            *(f16x4*)&attnh[((size_t)b * NTOK + r0 + ty * 4 + r) * CDIM + h * HD + tx * 4] = o4;
        }
        __syncthreads();
    }
}

extern "C" void kernel_launch(void* const* d_in, const int* in_sizes, int n_in,
                              void* d_out, int out_size, void* d_ws, size_t ws_size,
                              hipStream_t stream)
{
    const float* x      = (const float*)d_in[0];
    const float* w_qkv  = (const float*)d_in[1];
    const float* b_qkv  = (const float*)d_in[2];
    const float* w_proj = (const float*)d_in[3];
    const float* b_proj = (const float*)d_in[4];
    float* out = (float*)d_out;
    char*  ws  = (char*)d_ws;

    const size_t NCB = (size_t)M_ROWS * CDIM * sizeof(f16);   // 64 MiB
    f16*   xh   = (f16*)(ws);
    f16*   qh   = (f16*)(ws + NCB * 1);
    f16*   kh   = (f16*)(ws + NCB * 2);
    f16*   vh   = (f16*)(ws + NCB * 3);          // reused as attn_h after kv_kernel
    f16*   wqt  = (f16*)(ws + NCB * 4);
    f16*   wpt  = (f16*)(ws + NCB * 4 + (1536 * 512) * sizeof(f16));
    float* tab  = (float*)(ws + NCB * 4 + (1536 * 512 + 512 * 512) * sizeof(f16));
    float* kvp  = tab + 8192;
    float* ksum = kvp + 32 * 4096;

    hipMemsetAsync(kvp, 0, (32 * 4096 + 32 * 64) * sizeof(float), stream);
    rope_tables<<<1, 256, 0, stream>>>(tab);
    convert_x_f16<<<M_ROWS * CDIM / 8 / 256, 256, 0, stream>>>(x, xh);
    convert_wT<<<1536 * 512 / 256, 256, 0, stream>>>(w_qkv, wqt, 1536);
    convert_wT<<<512 * 512 / 256, 256, 0, stream>>>(w_proj, wpt, 512);

    gemm_f16<1><<<dim3(12, 512), 256, 0, stream>>>(xh, wqt, b_qkv,
                                                   nullptr, qh, kh, vh, tab);
    kv_kernel<<<dim3(32, 16), 256, 0, stream>>>(kh, vh, kvp, ksum);
    attn_kernel<<<dim3(32, 64), 256, 0, stream>>>(qh, kvp, ksum, vh);
    gemm_f16<0><<<dim3(4, 512), 256, 0, stream>>>(vh, wpt, b_proj,
                                                  out, nullptr, nullptr, nullptr, nullptr);
}

// Round 3
// 657.841 us; speedup vs baseline: 2.9714x; 1.0203x over previous
//
#include <hip/hip_runtime.h>
#include <math.h>

#define BATCH 4
#define NTOK  16384
#define CDIM  512
#define NH    8
#define HD    64
#define M_ROWS (BATCH*NTOK)
#define KDIM  512

typedef _Float16 f16;
typedef _Float16 f16x8 __attribute__((ext_vector_type(8)));
typedef _Float16 f16x4 __attribute__((ext_vector_type(4)));
typedef _Float16 f16x2 __attribute__((ext_vector_type(2)));
typedef float    f32x4 __attribute__((ext_vector_type(4)));

__device__ __forceinline__ void load_lds16(const void* g, void* l) {
    __builtin_amdgcn_global_load_lds(
        (const __attribute__((address_space(1))) void*)g,
        (__attribute__((address_space(3))) void*)l, 16, 0, 0);
}

__global__ void rope_tables(float* __restrict__ tab) {
    int tid = threadIdx.x;
    for (int i = 0; i < 32; i++) {
        int idx = tid + i * 256;
        int grp = idx >> 11;
        int rem = idx & 2047;
        int t   = rem >> 4;
        int fi  = rem & 15;
        float freq_f = (float)pow(10.0, -(double)fi / 16.0);
        double ang = (double)t * (double)freq_f;
        tab[idx] = (float)((grp & 1) ? sin(ang) : cos(ang));
    }
}

__global__ void convert_x_f16(const float* __restrict__ in, f16* __restrict__ outp) {
    int i = blockIdx.x * 256 + threadIdx.x;
    float4 a = *(const float4*)&in[(size_t)i * 8];
    float4 b = *(const float4*)&in[(size_t)i * 8 + 4];
    f16x8 o;
    o[0]=(f16)a.x; o[1]=(f16)a.y; o[2]=(f16)a.z; o[3]=(f16)a.w;
    o[4]=(f16)b.x; o[5]=(f16)b.y; o[6]=(f16)b.z; o[7]=(f16)b.w;
    *(f16x8*)&outp[(size_t)i * 8] = o;
}

__global__ void convert_wT(const float* __restrict__ w, f16* __restrict__ wt, int N) {
    int idx = blockIdx.x * 256 + threadIdx.x;
    int n = idx >> 9, k = idx & 511;
    wt[idx] = (f16)w[(size_t)k * N + n];
}

// ---------------- fp16 MFMA GEMM, 128x128 tile, 2x BK=32 per barrier --------
// XCD-swizzled 1D grid: xcd = bid&7, col-tile fastest within an XCD so one
// A row-tile + B stay resident in that XCD's 4MB L2.
template<int MODE>
__global__ __launch_bounds__(256, 2)
void gemm_f16(const f16* __restrict__ A, const f16* __restrict__ Bt,
              const float* __restrict__ bias,
              float* __restrict__ Co,
              f16* __restrict__ qd, f16* __restrict__ kd, f16* __restrict__ vd,
              const float* __restrict__ tab, int ncol_tiles)
{
    __shared__ f16 As[2][128 * 32];
    __shared__ f16 Bs[2][128 * 32];
    const int tid  = threadIdx.x;
    const int lane = tid & 63;
    const int wave = tid >> 6;
    const int wy = wave >> 1, wx = wave & 1;

    const int bid = blockIdx.x;
    const int xcd = bid & 7;
    const int idx = bid >> 3;
    const int ct  = idx % ncol_tiles;
    const int rt  = (idx / ncol_tiles) * 8 + xcd;
    const int row0 = rt * 128;
    const int col0 = ct * 128;

    const int l15 = lane & 15;
    const int l4  = lane >> 4;

    f32x4 acc[4][4];
    #pragma unroll
    for (int mt = 0; mt < 4; mt++)
        #pragma unroll
        for (int nt = 0; nt < 4; nt++)
            acc[mt][nt] = (f32x4){0.f, 0.f, 0.f, 0.f};

    const int pbase = wave * 128;

    for (int k0 = 0; k0 < KDIM; k0 += 64) {
        #pragma unroll
        for (int s = 0; s < 2; s++)
            #pragma unroll
            for (int i = 0; i < 2; i++) {
                int p = pbase + i * 64 + lane;      // 16B chunk id 0..511
                int m = p >> 2;                     // tile row
                int j = p & 3;                      // chunk within 32-wide k
                load_lds16(&A [(size_t)(row0 + m) * KDIM + k0 + s * 32 + j * 8],
                           &As[s][(pbase + i * 64) * 8]);
                load_lds16(&Bt[(size_t)(col0 + m) * KDIM + k0 + s * 32 + j * 8],
                           &Bs[s][(pbase + i * 64) * 8]);
            }
        __syncthreads();

        #pragma unroll
        for (int s = 0; s < 2; s++) {
            f16x8 af[4], bf[4];
            #pragma unroll
            for (int t = 0; t < 4; t++) {
                af[t] = *(const f16x8*)&As[s][(wy * 64 + t * 16 + l15) * 32 + l4 * 8];
                bf[t] = *(const f16x8*)&Bs[s][(wx * 64 + t * 16 + l15) * 32 + l4 * 8];
            }
            #pragma unroll
            for (int mt = 0; mt < 4; mt++)
                #pragma unroll
                for (int nt = 0; nt < 4; nt++)
                    acc[mt][nt] = __builtin_amdgcn_mfma_f32_16x16x32_f16(af[mt], bf[nt], acc[mt][nt], 0, 0, 0);
        }
        __syncthreads();
    }

    if (MODE == 0) {
        // LDS-transpose epilogue: 4 steps of 32 rows x 128 cols fp32 (16 KB,
        // aliases As), flushed as fully-coalesced float4 stores.
        float* ep = (float*)&As[0][0];              // 32*128 floats
        #pragma unroll
        for (int mt = 0; mt < 4; mt++) {
            #pragma unroll
            for (int nt = 0; nt < 4; nt++) {
                int col = wx * 64 + nt * 16 + l15;
                float bv = bias[col0 + col];
                #pragma unroll
                for (int r = 0; r < 4; r++) {
                    int rp = wy * 16 + l4 * 4 + r;  // 0..31
                    ep[rp * 128 + col] = acc[mt][nt][r] + bv;
                }
            }
            __syncthreads();
            #pragma unroll
            for (int j = 0; j < 4; j++) {
                int id = tid + j * 256;             // 0..1023 float4s
                int rp = id >> 5, c4 = id & 31;
                int grow = row0 + (rp >> 4) * 64 + mt * 16 + (rp & 15);
                float4 v4 = *(const float4*)&ep[rp * 128 + c4 * 4];
                *(float4*)&Co[(size_t)grow * CDIM + col0 + c4 * 4] = v4;
            }
            __syncthreads();
        }
    } else {
        const int which = col0 >> 9;
        f16* dst = (which == 0) ? qd : (which == 1) ? kd : vd;
        #pragma unroll
        for (int nt = 0; nt < 4; nt++) {
            int coln = col0 + wx * 64 + nt * 16 + l15;
            int c512 = coln & 511;
            float bv = bias[coln];
            if (which == 2) {
                #pragma unroll
                for (int mt = 0; mt < 4; mt++)
                    #pragma unroll
                    for (int r = 0; r < 4; r++) {
                        int row = row0 + wy * 64 + mt * 16 + l4 * 4 + r;
                        float val = acc[mt][nt][r] + bv;
                        float pv  = __shfl_xor(val, 1, 64);
                        if (!(lane & 1)) {
                            f16x2 pk; pk[0] = (f16)val; pk[1] = (f16)pv;
                            *(f16x2*)&dst[(size_t)row * CDIM + c512] = pk;
                        }
                    }
            } else {
                int ch  = c512 & 63;
                int isy = ch >> 5;
                int fid = (ch & 31) >> 1;
                const float* ctb = tab + (isy ? 4096 : 0)    + fid;
                const float* stb = tab + (isy ? 6144 : 2048) + fid;
                #pragma unroll
                for (int mt = 0; mt < 4; mt++)
                    #pragma unroll
                    for (int r = 0; r < 4; r++) {
                        int row = row0 + wy * 64 + mt * 16 + l4 * 4 + r;
                        int tok = row & (NTOK - 1);
                        int t   = isy ? (tok >> 7) : (tok & 127);
                        float c = ctb[t * 16], s = stb[t * 16];
                        float val = acc[mt][nt][r] + bv;
                        float pv  = __shfl_xor(val, 1, 64);
                        float xr = (lane & 1) ? pv  : val;
                        float xi = (lane & 1) ? val : pv;
                        float o_r = xr * c - xi * s;
                        float o_i = xr * s + xi * c;
                        o_r = (o_r > 0.f) ? o_r + 1.f : __expf(o_r);
                        o_i = (o_i > 0.f) ? o_i + 1.f : __expf(o_i);
                        if (!(lane & 1)) {
                            f16x2 pk; pk[0] = (f16)o_r; pk[1] = (f16)o_i;
                            *(f16x2*)&dst[(size_t)row * CDIM + c512] = pk;
                        }
                    }
            }
        }
    }
}

__global__ __launch_bounds__(256, 4)
void kv_kernel(const f16* __restrict__ kk, const f16* __restrict__ vv,
               float* __restrict__ kv, float* __restrict__ ksum)
{
    int bh = blockIdx.x;
    int b = bh >> 3, h = bh & 7;
    int t0 = blockIdx.y * 1024;
    __shared__ float ks[64][68];
    __shared__ float vs[64][68];
    int tid = threadIdx.x;
    int tx = tid & 15;
    int ty = tid >> 4;
    float acc[4][4];
    float ksacc[4];
    #pragma unroll
    for (int r = 0; r < 4; r++) { ksacc[r] = 0.f;
        #pragma unroll
        for (int j = 0; j < 4; j++) acc[r][j] = 0.f; }

    const size_t rowbase = (size_t)b * NTOK;
    for (int tt = t0; tt < t0 + 1024; tt += 64) {
        #pragma unroll
        for (int i = 0; i < 2; i++) {
            int idx = tid + i * 256;
            int tok = idx >> 3;
            int o   = (idx & 7) * 8;
            size_t g = (rowbase + tt + tok) * CDIM + h * HD + o;
            f16x8 k8 = *(const f16x8*)&kk[g];
            f16x8 v8 = *(const f16x8*)&vv[g];
            float4 klo = {(float)k8[0], (float)k8[1], (float)k8[2], (float)k8[3]};
            float4 khi = {(float)k8[4], (float)k8[5], (float)k8[6], (float)k8[7]};
            float4 vlo = {(float)v8[0], (float)v8[1], (float)v8[2], (float)v8[3]};
            float4 vhi = {(float)v8[4], (float)v8[5], (float)v8[6], (float)v8[7]};
            *(float4*)&ks[tok][o]     = klo;
            *(float4*)&ks[tok][o + 4] = khi;
            *(float4*)&vs[tok][o]     = vlo;
            *(float4*)&vs[tok][o + 4] = vhi;
        }
        __syncthreads();
        #pragma unroll 8
        for (int t = 0; t < 64; t++) {
            float4 kd4 = *(const float4*)&ks[t][ty * 4];
            float4 vd4 = *(const float4*)&vs[t][tx * 4];
            float ka[4] = {kd4.x, kd4.y, kd4.z, kd4.w};
            float va[4] = {vd4.x, vd4.y, vd4.z, vd4.w};
            #pragma unroll
            for (int r = 0; r < 4; r++) {
                ksacc[r] += ka[r];
                #pragma unroll
                for (int j = 0; j < 4; j++) acc[r][j] += ka[r] * va[j];
            }
        }
        __syncthreads();
    }
    #pragma unroll
    for (int r = 0; r < 4; r++)
        #pragma unroll
        for (int j = 0; j < 4; j++)
            atomicAdd(&kv[bh * 4096 + (ty * 4 + r) * 64 + tx * 4 + j], acc[r][j]);
    if (tx == 0) {
        #pragma unroll
        for (int r = 0; r < 4; r++) atomicAdd(&ksum[bh * 64 + ty * 4 + r], ksacc[r]);
    }
}

__global__ __launch_bounds__(256, 4)
void attn_kernel(const f16* __restrict__ q, const float* __restrict__ kv,
                 const float* __restrict__ ksum, f16* __restrict__ attnh)
{
    int bh = blockIdx.x;
    int b = bh >> 3, h = bh & 7;
    int rc = blockIdx.y;
    __shared__ float kvs[64][68];
    __shared__ float qs[64][68];
    __shared__ float ksums[64];
    __shared__ float zpart[64][4];
    __shared__ float zs[64];
    int tid = threadIdx.x;
    int tx = tid & 15;
    int ty = tid >> 4;

    #pragma unroll
    for (int i = 0; i < 4; i++) {
        int idx = tid + i * 256;
        *(float4*)&kvs[idx >> 4][(idx & 15) * 4] = *(const float4*)&kv[bh * 4096 + idx * 4];
    }
    if (tid < 64) ksums[tid] = ksum[bh * 64 + tid];

    for (int sub = 0; sub < 4; sub++) {
        int r0 = rc * 256 + sub * 64;
        #pragma unroll
        for (int i = 0; i < 2; i++) {
            int idx = tid + i * 256;
            int rr = idx >> 3;
            int o  = (idx & 7) * 8;
            f16x8 q8 = *(const f16x8*)&q[((size_t)b * NTOK + r0 + rr) * CDIM + h * HD + o];
            float4 lo = {(float)q8[0], (float)q8[1], (float)q8[2], (float)q8[3]};
            float4 hi = {(float)q8[4], (float)q8[5], (float)q8[6], (float)q8[7]};
            *(float4*)&qs[rr][o]     = lo;
            *(float4*)&qs[rr][o + 4] = hi;
        }
        __syncthreads();
        {
            int row = tid & 63, g = tid >> 6;
            float p = 0.f;
            #pragma unroll
            for (int d = 0; d < 16; d++) p += qs[row][g * 16 + d] * ksums[g * 16 + d];
            zpart[row][g] = p;
        }
        __syncthreads();
        if (tid < 64)
            zs[tid] = 1.f / (zpart[tid][0] + zpart[tid][1] + zpart[tid][2] + zpart[tid][3] + 1e-6f);
        __syncthreads();

        float acc[4][4];
        #pragma unroll
        for (int r = 0; r < 4; r++)
            #pragma unroll
            for (int e = 0; e < 4; e++) acc[r][e] = 0.f;

        for (int d = 0; d < 64; d += 4) {
            float qa[4][4], ka[4][4];
            #pragma unroll
            for (int r = 0; r < 4; r++) {
                float4 v4 = *(const float4*)&qs[ty * 4 + r][d];
                qa[r][0]=v4.x; qa[r][1]=v4.y; qa[r][2]=v4.z; qa[r][3]=v4.w;
            }
            #pragma unroll
            for (int j = 0; j < 4; j++) {
                float4 v4 = *(const float4*)&kvs[d + j][tx * 4];
                ka[j][0]=v4.x; ka[j][1]=v4.y; ka[j][2]=v4.z; ka[j][3]=v4.w;
            }
            #pragma unroll
            for (int r = 0; r < 4; r++)
                #pragma unroll
                for (int j = 0; j < 4; j++)
                    #pragma unroll
                    for (int e = 0; e < 4; e++)
                        acc[r][e] += qa[r][j] * ka[j][e];
        }
        #pragma unroll
        for (int r = 0; r < 4; r++) {
            float z = zs[ty * 4 + r];
            f16x4 o4;
            o4[0] = (f16)(acc[r][0] * z); o4[1] = (f16)(acc[r][1] * z);
            o4[2] = (f16)(acc[r][2] * z); o4[3] = (f16)(acc[r][3] * z);
            *(f16x4*)&attnh[((size_t)b * NTOK + r0 + ty * 4 + r) * CDIM + h * HD + tx * 4] = o4;
        }
        __syncthreads();
    }
}

extern "C" void kernel_launch(void* const* d_in, const int* in_sizes, int n_in,
                              void* d_out, int out_size, void* d_ws, size_t ws_size,
                              hipStream_t stream)
{
    const float* x      = (const float*)d_in[0];
    const float* w_qkv  = (const float*)d_in[1];
    const float* b_qkv  = (const float*)d_in[2];
    const float* w_proj = (const float*)d_in[3];
    const float* b_proj = (const float*)d_in[4];
    float* out = (float*)d_out;
    char*  ws  = (char*)d_ws;

    const size_t NCB = (size_t)M_ROWS * CDIM * sizeof(f16);   // 64 MiB
    f16*   xh   = (f16*)(ws);
    f16*   qh   = (f16*)(ws + NCB * 1);
    f16*   kh   = (f16*)(ws + NCB * 2);
    f16*   vh   = (f16*)(ws + NCB * 3);          // reused as attn_h after kv_kernel
    f16*   wqt  = (f16*)(ws + NCB * 4);
    f16*   wpt  = (f16*)(ws + NCB * 4 + (1536 * 512) * sizeof(f16));
    float* tab  = (float*)(ws + NCB * 4 + (1536 * 512 + 512 * 512) * sizeof(f16));
    float* kvp  = tab + 8192;
    float* ksum = kvp + 32 * 4096;

    hipMemsetAsync(kvp, 0, (32 * 4096 + 32 * 64) * sizeof(float), stream);
    rope_tables<<<1, 256, 0, stream>>>(tab);
    convert_x_f16<<<M_ROWS * CDIM / 8 / 256, 256, 0, stream>>>(x, xh);
    convert_wT<<<1536 * 512 / 256, 256, 0, stream>>>(w_qkv, wqt, 1536);
    convert_wT<<<512 * 512 / 256, 256, 0, stream>>>(w_proj, wpt, 512);

    gemm_f16<1><<<6144, 256, 0, stream>>>(xh, wqt, b_qkv,
                                          nullptr, qh, kh, vh, tab, 12);
    kv_kernel<<<dim3(32, 16), 256, 0, stream>>>(kh, vh, kvp, ksum);
    attn_kernel<<<dim3(32, 64), 256, 0, stream>>>(qh, kvp, ksum, vh);
    gemm_f16<0><<<2048, 256, 0, stream>>>(vh, wpt, b_proj,
                                          out, nullptr, nullptr, nullptr, nullptr, 4);
}